// Round 3
// baseline (1228.044 us; speedup 1.0000x reference)
//
#include <hip/hip_runtime.h>
#include <hip/hip_bf16.h>

#define N_NODES 100000
#define N_EDGES 1600000
#define H 128
#define NUM_INV 16
#define BN_EPS 1e-5f

typedef __attribute__((ext_vector_type(8))) short short8;
typedef __attribute__((ext_vector_type(4))) float f32x4;
typedef __attribute__((ext_vector_type(2))) float f32x2;

static __device__ __forceinline__ unsigned short f2b(float x) {
    union { float f; unsigned u; } c; c.f = x;
    unsigned r = c.u + 0x7fffu + ((c.u >> 16) & 1u);
    return (unsigned short)(r >> 16);
}
static __device__ __forceinline__ float b2f(unsigned short u) {
    union { unsigned u; float f; } c; c.u = ((unsigned)u) << 16; return c.f;
}
// packed bf16x2 (one dword) -> f32x2
static __device__ __forceinline__ f32x2 b2f2(unsigned u) {
    union { unsigned u; float f; } lo, hi;
    lo.u = u << 16;
    hi.u = u & 0xffff0000u;
    return (f32x2){lo.f, hi.f};
}
static __device__ __forceinline__ f32x2 splat2(float s) { return (f32x2){s, s}; }

// DPP-based wave64 sum: result valid in lane 63
template<int CTRL, int RM>
static __device__ __forceinline__ float dppadd(float x) {
    union { float f; int i; } u, s;
    u.f = x;
    s.i = __builtin_amdgcn_update_dpp(0, u.i, CTRL, RM, 0xf, true);
    return x + s.f;
}
static __device__ __forceinline__ float wave_sum_bcast(float p) {
    p = dppadd<0x111, 0xf>(p);   // row_shr:1
    p = dppadd<0x112, 0xf>(p);   // row_shr:2
    p = dppadd<0x114, 0xf>(p);   // row_shr:4
    p = dppadd<0x118, 0xf>(p);   // row_shr:8
    p = dppadd<0x142, 0xa>(p);   // row_bcast:15 -> rows 1,3
    p = dppadd<0x143, 0xc>(p);   // row_bcast:31 -> rows 2,3
    union { float f; int i; } u, r;
    u.f = p;
    r.i = __builtin_amdgcn_readlane(u.i, 63);
    return r.f;
}

// ---------------- K0: W1[0:256,:] -> bf16, transposed ----------------------------------
__global__ void k0_wt(const float* __restrict__ W1, unsigned short* __restrict__ Wt) {
    int idx = blockIdx.x * blockDim.x + threadIdx.x;
    if (idx >= 2 * H * H) return;
    int g = idx >> 14;
    int rem = idx & 16383;
    int k = rem >> 7;
    int f = rem & 127;
    Wt[(size_t)g * H * H + (size_t)f * H + k] = f2b(W1[(size_t)(g * H + k) * H + f]);
}

// ---------------- K1: P = X @ W1part (+b1 for send), bf16 MFMA, M-tile 32 ---------------
__global__ __launch_bounds__(256) void k1_gemm(
    const float* __restrict__ x_send, const float* __restrict__ x_rec,
    const unsigned short* __restrict__ Wt, const float* __restrict__ b1,
    unsigned short* __restrict__ P_send, unsigned short* __restrict__ P_rec)
{
    const int g = blockIdx.y;
    const float* X = g ? x_rec : x_send;
    unsigned short* P = g ? P_rec : P_send;
    const int m0 = blockIdx.x * 32;
    const int tid = threadIdx.x;
    const int wave = tid >> 6;
    const int lane = tid & 63;
    const int quad = lane >> 4;
    const int l16 = lane & 15;
    const int n0 = wave * 32;

    const unsigned short* Wg = Wt + (size_t)g * (H * H);

    f32x4 acc[2][2];
    #pragma unroll
    for (int i = 0; i < 2; ++i)
        #pragma unroll
        for (int j = 0; j < 2; ++j)
            acc[i][j] = (f32x4){0.f, 0.f, 0.f, 0.f};

    #pragma unroll
    for (int kt = 0; kt < 4; ++kt) {
        const int kk = kt * 32;
        short8 a[2], b[2];
        #pragma unroll
        for (int ms = 0; ms < 2; ++ms) {
            const float* ap = X + (size_t)(m0 + ms * 16 + l16) * H + kk + quad * 8;
            f32x4 a0 = *(const f32x4*)ap;
            f32x4 a1 = *(const f32x4*)(ap + 4);
            short8 t;
            t[0] = (short)f2b(a0[0]); t[1] = (short)f2b(a0[1]);
            t[2] = (short)f2b(a0[2]); t[3] = (short)f2b(a0[3]);
            t[4] = (short)f2b(a1[0]); t[5] = (short)f2b(a1[1]);
            t[6] = (short)f2b(a1[2]); t[7] = (short)f2b(a1[3]);
            a[ms] = t;
        }
        #pragma unroll
        for (int ns = 0; ns < 2; ++ns)
            b[ns] = *(const short8*)(Wg + (size_t)(n0 + ns * 16 + l16) * H + kk + quad * 8);
        #pragma unroll
        for (int ms = 0; ms < 2; ++ms)
            #pragma unroll
            for (int ns = 0; ns < 2; ++ns)
                acc[ms][ns] = __builtin_amdgcn_mfma_f32_16x16x32_bf16(
                    a[ms], b[ns], acc[ms][ns], 0, 0, 0);
    }

    #pragma unroll
    for (int ms = 0; ms < 2; ++ms) {
        #pragma unroll
        for (int ns = 0; ns < 2; ++ns) {
            int col = n0 + ns * 16 + l16;
            float bias = g ? 0.f : b1[col];
            #pragma unroll
            for (int r = 0; r < 4; ++r) {
                int row = m0 + ms * 16 + quad * 4 + r;
                P[(size_t)row * H + col] = f2b(acc[ms][ns][r] + bias);
            }
        }
    }
}

// ---------------- CSR build ------------------------------------------------------------
__global__ void k_deg(const int* __restrict__ irec, int* __restrict__ deg) {
    int e = blockIdx.x * 256 + threadIdx.x;
    if (e < N_EDGES) atomicAdd(&deg[irec[e]], 1);
}

__global__ __launch_bounds__(512) void k_scanA(const int* __restrict__ deg, int* __restrict__ bsum) {
    __shared__ int sh[512];
    int t = threadIdx.x;
    int n = blockIdx.x * 512 + t;
    int v = (n < N_NODES) ? deg[n] : 0;
    sh[t] = v; __syncthreads();
    for (int d = 1; d < 512; d <<= 1) {
        int x = (t >= d) ? sh[t - d] : 0;
        __syncthreads();
        sh[t] += x;
        __syncthreads();
    }
    if (t == 511) bsum[blockIdx.x] = sh[511];
}

__global__ __launch_bounds__(256) void k_scanB(const int* __restrict__ bsum, int* __restrict__ bbase) {
    __shared__ int sh[256];
    int t = threadIdx.x;
    int v = (t < 196) ? bsum[t] : 0;
    sh[t] = v; __syncthreads();
    for (int d = 1; d < 256; d <<= 1) {
        int x = (t >= d) ? sh[t - d] : 0;
        __syncthreads();
        sh[t] += x;
        __syncthreads();
    }
    if (t < 196) bbase[t] = sh[t] - v;   // exclusive
}

__global__ __launch_bounds__(512) void k_scanC(const int* __restrict__ deg, const int* __restrict__ bbase,
                                               int* __restrict__ off, int* __restrict__ cursor) {
    __shared__ int sh[512];
    int t = threadIdx.x;
    int n = blockIdx.x * 512 + t;
    int v = (n < N_NODES) ? deg[n] : 0;
    sh[t] = v; __syncthreads();
    for (int d = 1; d < 512; d <<= 1) {
        int x = (t >= d) ? sh[t - d] : 0;
        __syncthreads();
        sh[t] += x;
        __syncthreads();
    }
    if (n < N_NODES) {
        int o = bbase[blockIdx.x] + sh[t] - v;   // exclusive prefix
        off[n] = o;
        cursor[n] = o;
    }
}

__global__ void k_perm(const int* __restrict__ irec, const int* __restrict__ isend,
                       int* __restrict__ cursor,
                       int* __restrict__ perm, int* __restrict__ is_csr) {
    int e = blockIdx.x * 256 + threadIdx.x;
    if (e >= N_EDGES) return;
    int p = atomicAdd(&cursor[irec[e]], 1);
    perm[p] = e;
    is_csr[p] = isend[e];
}

// ---------------- K2: BN stats (sum, sumsq per feature), packed fp32 --------------------
__global__ __launch_bounds__(256) void k2_stats(
    const unsigned short* __restrict__ Ps, const unsigned short* __restrict__ Pr,
    const int* __restrict__ isend, const int* __restrict__ irec,
    const float* __restrict__ ea, const float* __restrict__ W1,
    float* __restrict__ stats)
{
    const int tid = threadIdx.x;
    const int wave = tid >> 6;
    const int lane = tid & 63;
    const int f0 = lane * 2;
    const float* Wc = W1 + 2 * H * H;

    int z = 0;
    asm volatile("" : "+v"(z));            // opaque 0: keeps ea loads in VGPRs
    const float* eab = ea + z;

    f32x2 wc2[NUM_INV];
    #pragma unroll
    for (int k = 0; k < NUM_INV; ++k)
        wc2[k] = (f32x2){Wc[k * H + f0], Wc[k * H + f0 + 1]};

    f32x2 s2 = {0.f, 0.f}, q2 = {0.f, 0.f};
    int wid = blockIdx.x * 4 + wave;
    int nw = gridDim.x * 4;
    for (int e = wid; e < N_EDGES; e += nw) {
        int eu = __builtin_amdgcn_readfirstlane(e);
        int is = isend[eu], ir = irec[eu];
        unsigned ua = *(const unsigned*)(Ps + (size_t)is * H + f0);
        unsigned ub = *(const unsigned*)(Pr + (size_t)ir * H + f0);
        f32x2 h2 = b2f2(ua) + b2f2(ub);
        const f32x4* ep = (const f32x4*)(eab + (size_t)eu * NUM_INV);
        f32x4 e0 = ep[0], e1 = ep[1], e2 = ep[2], e3 = ep[3];
        float ev[16] = {e0[0],e0[1],e0[2],e0[3], e1[0],e1[1],e1[2],e1[3],
                        e2[0],e2[1],e2[2],e2[3], e3[0],e3[1],e3[2],e3[3]};
        #pragma unroll
        for (int k = 0; k < NUM_INV; ++k) h2 += splat2(ev[k]) * wc2[k];
        s2 += h2;
        q2 += h2 * h2;
    }

    __shared__ float rs[4][128];
    __shared__ float rq[4][128];
    rs[wave][f0] = s2.x; rs[wave][f0 + 1] = s2.y;
    rq[wave][f0] = q2.x; rq[wave][f0 + 1] = q2.y;
    __syncthreads();
    if (tid < 128) {
        float ss = rs[0][tid] + rs[1][tid] + rs[2][tid] + rs[3][tid];
        float qq = rq[0][tid] + rq[1][tid] + rq[2][tid] + rq[3][tid];
        float* st = stats + (size_t)(blockIdx.x & 63) * 256;
        atomicAdd(st + tid, ss);
        atomicAdd(st + 128 + tid, qq);
    }
}

// ---------------- K3: finalize BN -> per-feature scale/shift ----------------------------
__global__ void k3_finalize(const float* __restrict__ stats,
                            const float* __restrict__ gamma, const float* __restrict__ beta,
                            float* __restrict__ ssb)
{
    int f = threadIdx.x;
    if (f >= H) return;
    float s = 0.f, q = 0.f;
    for (int b = 0; b < 64; ++b) {
        s += stats[b * 256 + f];
        q += stats[b * 256 + 128 + f];
    }
    const float invE = 1.f / (float)N_EDGES;
    float mean = s * invE;
    float var = q * invE - mean * mean;
    float scale = gamma[f] * rsqrtf(var + BN_EPS);
    ssb[f] = scale;
    ssb[H + f] = beta[f] - mean * scale;
}

// ---------------- K4: CSR pass 2 — atomic-free, packed fp32, DPP reduce -----------------
__global__ __launch_bounds__(256) void k4_csr(
    const unsigned short* __restrict__ Ps, const unsigned short* __restrict__ Pr,
    const int* __restrict__ perm, const int* __restrict__ is_csr,
    const float* __restrict__ ea, const float* __restrict__ W1,
    const int* __restrict__ off, const int* __restrict__ deg,
    const float* __restrict__ ssb, const float* __restrict__ Winf,
    const float* __restrict__ binf_p, float* __restrict__ out)
{
    const int tid = threadIdx.x;
    const int wave = tid >> 6;
    const int lane = tid & 63;
    const int f0 = lane * 2;
    const float* Wc = W1 + 2 * H * H;

    int z = 0;
    asm volatile("" : "+v"(z));            // opaque 0: keeps ea loads in VGPRs
    const float* eab = ea + z;

    f32x2 wc2[NUM_INV];
    #pragma unroll
    for (int k = 0; k < NUM_INV; ++k)
        wc2[k] = (f32x2){Wc[k * H + f0], Wc[k * H + f0 + 1]};

    int n = blockIdx.x * 4 + wave;
    int nu = __builtin_amdgcn_readfirstlane(n);
    int start = off[nu];
    int d = deg[nu];

    unsigned ub = *(const unsigned*)(Pr + (size_t)nu * H + f0);
    f32x2 pr2 = b2f2(ub);

    f32x2 sc2 = (f32x2){ssb[f0], ssb[f0 + 1]};
    f32x2 sh2 = (f32x2){ssb[H + f0], ssb[H + f0 + 1]};
    f32x2 wi2 = (f32x2){Winf[f0], Winf[f0 + 1]};
    float bi = binf_p[0];

    f32x2 a2 = {0.f, 0.f};
    for (int i = 0; i < d; ++i) {
        int e = perm[start + i];       // wave-uniform scalar load
        int is = is_csr[start + i];    // independent scalar load
        unsigned ua = *(const unsigned*)(Ps + (size_t)is * H + f0);
        f32x2 h2 = pr2 + b2f2(ua);
        const f32x4* ep = (const f32x4*)(eab + (size_t)e * NUM_INV);
        f32x4 e0 = ep[0], e1 = ep[1], e2 = ep[2], e3 = ep[3];
        float ev[16] = {e0[0],e0[1],e0[2],e0[3], e1[0],e1[1],e1[2],e1[3],
                        e2[0],e2[1],e2[2],e2[3], e3[0],e3[1],e3[2],e3[3]};
        #pragma unroll
        for (int k = 0; k < NUM_INV; ++k) h2 += splat2(ev[k]) * wc2[k];
        h2 = h2 * sc2 + sh2;
        // silu pair with single reciprocal: m = h * sigmoid(h)
        float A = 1.f + __expf(-h2.x);
        float B = 1.f + __expf(-h2.y);
        float r = __builtin_amdgcn_rcpf(A * B);
        f32x2 m2 = (f32x2){h2.x * B * r, h2.y * A * r};
        f32x2 pp = m2 * wi2;
        float ptot = wave_sum_bcast(pp.x + pp.y);
        float ew = __builtin_amdgcn_rcpf(1.f + __expf(-(ptot + bi)));
        a2 += m2 * splat2(ew);
    }
    *(float2*)(out + (size_t)nu * H + f0) = make_float2(a2.x, a2.y);
}

// ---------------- launcher --------------------------------------------------------------
extern "C" void kernel_launch(void* const* d_in, const int* in_sizes, int n_in,
                              void* d_out, int out_size, void* d_ws, size_t ws_size,
                              hipStream_t stream)
{
    const float* x_send = (const float*)d_in[0];
    const float* x_rec  = (const float*)d_in[1];
    const int*   isend  = (const int*)d_in[2];
    const int*   irec   = (const int*)d_in[3];
    const float* ea     = (const float*)d_in[4];
    const float* W1     = (const float*)d_in[5];
    const float* b1     = (const float*)d_in[6];
    const float* gamma  = (const float*)d_in[7];
    const float* beta   = (const float*)d_in[8];
    const float* Winf   = (const float*)d_in[9];
    const float* binf   = (const float*)d_in[10];
    float* out = (float*)d_out;

    char* ws = (char*)d_ws;
    unsigned short* Ps = (unsigned short*)(ws);                     // 25,600,000
    unsigned short* Pr = (unsigned short*)(ws + 25600000);          // 25,600,000
    unsigned short* Wt = (unsigned short*)(ws + 51200000);          // 65,536
    float* stats       = (float*)(ws + 51265536);                   // 65,536
    float* ssb         = (float*)(ws + 51331072);                   // 1,024
    int* deg           = (int*)(ws + 51332096);                     // 400,000
    int* off           = (int*)(ws + 51732096);                     // 400,000
    int* cursor        = (int*)(ws + 52132096);                     // 400,000
    int* bsum          = (int*)(ws + 52532096);                     // 1,024
    int* bbase         = (int*)(ws + 52533120);                     // 1,024
    int* perm          = (int*)(ws + 52534144);                     // 6,400,000
    int* is_csr        = (int*)(ws + 58934144);                     // 6,400,000 -> 65,334,144

    hipMemsetAsync(stats, 0, 64 * 256 * sizeof(float), stream);
    hipMemsetAsync(deg, 0, N_NODES * sizeof(int), stream);

    k0_wt<<<(2 * H * H + 255) / 256, 256, 0, stream>>>(W1, Wt);
    dim3 g1(3125, 2, 1);
    k1_gemm<<<g1, 256, 0, stream>>>(x_send, x_rec, Wt, b1, Ps, Pr);

    k_deg<<<N_EDGES / 256, 256, 0, stream>>>(irec, deg);
    k_scanA<<<196, 512, 0, stream>>>(deg, bsum);
    k_scanB<<<1, 256, 0, stream>>>(bsum, bbase);
    k_scanC<<<196, 512, 0, stream>>>(deg, bbase, off, cursor);
    k_perm<<<N_EDGES / 256, 256, 0, stream>>>(irec, isend, cursor, perm, is_csr);

    k2_stats<<<2048, 256, 0, stream>>>(Ps, Pr, isend, irec, ea, W1, stats);
    k3_finalize<<<1, 128, 0, stream>>>(stats, gamma, beta, ssb);
    k4_csr<<<N_NODES / 4, 256, 0, stream>>>(Ps, Pr, perm, is_csr, ea, W1, off, deg,
                                            ssb, Winf, binf, out);
}

// Round 4
// 1048.661 us; speedup vs baseline: 1.1711x; 1.1711x over previous
//
#include <hip/hip_runtime.h>
#include <hip/hip_bf16.h>

#define N_NODES 100000
#define N_EDGES 1600000
#define H 128
#define NUM_INV 16
#define BN_EPS 1e-5f

typedef __attribute__((ext_vector_type(8))) short short8;
typedef __attribute__((ext_vector_type(4))) float f32x4;
typedef __attribute__((ext_vector_type(2))) float f32x2;

static __device__ __forceinline__ unsigned short f2b(float x) {
    union { float f; unsigned u; } c; c.f = x;
    unsigned r = c.u + 0x7fffu + ((c.u >> 16) & 1u);
    return (unsigned short)(r >> 16);
}
// packed bf16x2 (one dword) -> f32x2
static __device__ __forceinline__ f32x2 b2f2(unsigned u) {
    union { unsigned u; float f; } lo, hi;
    lo.u = u << 16;
    hi.u = u & 0xffff0000u;
    return (f32x2){lo.f, hi.f};
}
static __device__ __forceinline__ f32x2 splat2(float s) { return (f32x2){s, s}; }

// DPP-based wave64 sum: broadcast result to all lanes
template<int CTRL, int RM>
static __device__ __forceinline__ float dppadd(float x) {
    union { float f; int i; } u, s;
    u.f = x;
    s.i = __builtin_amdgcn_update_dpp(0, u.i, CTRL, RM, 0xf, true);
    return x + s.f;
}
static __device__ __forceinline__ float wave_sum_bcast(float p) {
    p = dppadd<0x111, 0xf>(p);   // row_shr:1
    p = dppadd<0x112, 0xf>(p);   // row_shr:2
    p = dppadd<0x114, 0xf>(p);   // row_shr:4
    p = dppadd<0x118, 0xf>(p);   // row_shr:8
    p = dppadd<0x142, 0xa>(p);   // row_bcast:15 -> rows 1,3
    p = dppadd<0x143, 0xc>(p);   // row_bcast:31 -> rows 2,3
    union { float f; int i; } u, r;
    u.f = p;
    r.i = __builtin_amdgcn_readlane(u.i, 63);
    return r.f;
}

// per-edge MAC of edge_attr @ Wc (ea in SGPRs: e must be wave-uniform)
static __device__ __forceinline__ f32x2 ea_mac(const float* __restrict__ ea, int e,
                                               const f32x2* wc2, f32x2 h2) {
    const f32x4* ep = (const f32x4*)(ea + (size_t)e * NUM_INV);
    f32x4 e0 = ep[0], e1 = ep[1], e2 = ep[2], e3 = ep[3];
    float ev[16] = {e0[0],e0[1],e0[2],e0[3], e1[0],e1[1],e1[2],e1[3],
                    e2[0],e2[1],e2[2],e2[3], e3[0],e3[1],e3[2],e3[3]};
    #pragma unroll
    for (int k = 0; k < NUM_INV; ++k) h2 += splat2(ev[k]) * wc2[k];
    return h2;
}

// ---------------- K0: W1[0:256,:] -> bf16, transposed ----------------------------------
__global__ void k0_wt(const float* __restrict__ W1, unsigned short* __restrict__ Wt) {
    int idx = blockIdx.x * blockDim.x + threadIdx.x;
    if (idx >= 2 * H * H) return;
    int g = idx >> 14;
    int rem = idx & 16383;
    int k = rem >> 7;
    int f = rem & 127;
    Wt[(size_t)g * H * H + (size_t)f * H + k] = f2b(W1[(size_t)(g * H + k) * H + f]);
}

// ---------------- K1: P = X @ W1part (+b1 for send), bf16 MFMA, M-tile 32 ---------------
__global__ __launch_bounds__(256) void k1_gemm(
    const float* __restrict__ x_send, const float* __restrict__ x_rec,
    const unsigned short* __restrict__ Wt, const float* __restrict__ b1,
    unsigned short* __restrict__ P_send, unsigned short* __restrict__ P_rec)
{
    const int g = blockIdx.y;
    const float* X = g ? x_rec : x_send;
    unsigned short* P = g ? P_rec : P_send;
    const int m0 = blockIdx.x * 32;
    const int tid = threadIdx.x;
    const int wave = tid >> 6;
    const int lane = tid & 63;
    const int quad = lane >> 4;
    const int l16 = lane & 15;
    const int n0 = wave * 32;

    const unsigned short* Wg = Wt + (size_t)g * (H * H);

    f32x4 acc[2][2];
    #pragma unroll
    for (int i = 0; i < 2; ++i)
        #pragma unroll
        for (int j = 0; j < 2; ++j)
            acc[i][j] = (f32x4){0.f, 0.f, 0.f, 0.f};

    #pragma unroll
    for (int kt = 0; kt < 4; ++kt) {
        const int kk = kt * 32;
        short8 a[2], b[2];
        #pragma unroll
        for (int ms = 0; ms < 2; ++ms) {
            const float* ap = X + (size_t)(m0 + ms * 16 + l16) * H + kk + quad * 8;
            f32x4 a0 = *(const f32x4*)ap;
            f32x4 a1 = *(const f32x4*)(ap + 4);
            short8 t;
            t[0] = (short)f2b(a0[0]); t[1] = (short)f2b(a0[1]);
            t[2] = (short)f2b(a0[2]); t[3] = (short)f2b(a0[3]);
            t[4] = (short)f2b(a1[0]); t[5] = (short)f2b(a1[1]);
            t[6] = (short)f2b(a1[2]); t[7] = (short)f2b(a1[3]);
            a[ms] = t;
        }
        #pragma unroll
        for (int ns = 0; ns < 2; ++ns)
            b[ns] = *(const short8*)(Wg + (size_t)(n0 + ns * 16 + l16) * H + kk + quad * 8);
        #pragma unroll
        for (int ms = 0; ms < 2; ++ms)
            #pragma unroll
            for (int ns = 0; ns < 2; ++ns)
                acc[ms][ns] = __builtin_amdgcn_mfma_f32_16x16x32_bf16(
                    a[ms], b[ns], acc[ms][ns], 0, 0, 0);
    }

    #pragma unroll
    for (int ms = 0; ms < 2; ++ms) {
        #pragma unroll
        for (int ns = 0; ns < 2; ++ns) {
            int col = n0 + ns * 16 + l16;
            float bias = g ? 0.f : b1[col];
            #pragma unroll
            for (int r = 0; r < 4; ++r) {
                int row = m0 + ms * 16 + quad * 4 + r;
                P[(size_t)row * H + col] = f2b(acc[ms][ns][r] + bias);
            }
        }
    }
}

// ---------------- CSR build ------------------------------------------------------------
__global__ void k_deg(const int* __restrict__ irec, int* __restrict__ deg) {
    int e = blockIdx.x * 256 + threadIdx.x;
    if (e < N_EDGES) atomicAdd(&deg[irec[e]], 1);
}

__global__ __launch_bounds__(512) void k_scanA(const int* __restrict__ deg, int* __restrict__ bsum) {
    __shared__ int sh[512];
    int t = threadIdx.x;
    int n = blockIdx.x * 512 + t;
    int v = (n < N_NODES) ? deg[n] : 0;
    sh[t] = v; __syncthreads();
    for (int d = 1; d < 512; d <<= 1) {
        int x = (t >= d) ? sh[t - d] : 0;
        __syncthreads();
        sh[t] += x;
        __syncthreads();
    }
    if (t == 511) bsum[blockIdx.x] = sh[511];
}

__global__ __launch_bounds__(256) void k_scanB(const int* __restrict__ bsum, int* __restrict__ bbase) {
    __shared__ int sh[256];
    int t = threadIdx.x;
    int v = (t < 196) ? bsum[t] : 0;
    sh[t] = v; __syncthreads();
    for (int d = 1; d < 256; d <<= 1) {
        int x = (t >= d) ? sh[t - d] : 0;
        __syncthreads();
        sh[t] += x;
        __syncthreads();
    }
    if (t < 196) bbase[t] = sh[t] - v;   // exclusive
}

__global__ __launch_bounds__(512) void k_scanC(const int* __restrict__ deg, const int* __restrict__ bbase,
                                               int* __restrict__ off, int* __restrict__ cursor) {
    __shared__ int sh[512];
    int t = threadIdx.x;
    int n = blockIdx.x * 512 + t;
    int v = (n < N_NODES) ? deg[n] : 0;
    sh[t] = v; __syncthreads();
    for (int d = 1; d < 512; d <<= 1) {
        int x = (t >= d) ? sh[t - d] : 0;
        __syncthreads();
        sh[t] += x;
        __syncthreads();
    }
    if (n < N_NODES) {
        int o = bbase[blockIdx.x] + sh[t] - v;   // exclusive prefix
        off[n] = o;
        cursor[n] = o;
    }
}

__global__ void k_perm(const int* __restrict__ irec, const int* __restrict__ isend,
                       int* __restrict__ cursor,
                       int* __restrict__ perm, int* __restrict__ is_csr) {
    int e = blockIdx.x * 256 + threadIdx.x;
    if (e >= N_EDGES) return;
    int p = atomicAdd(&cursor[irec[e]], 1);
    perm[p] = e;
    is_csr[p] = isend[e];
}

// ---------------- K2: BN stats, edge-order, packed fp32, unroll-2 -----------------------
__global__ __launch_bounds__(256) void k2_stats(
    const unsigned short* __restrict__ Ps, const unsigned short* __restrict__ Pr,
    const int* __restrict__ isend, const int* __restrict__ irec,
    const float* __restrict__ ea, const float* __restrict__ W1,
    float* __restrict__ stats)
{
    const int tid = threadIdx.x;
    const int wave = tid >> 6;
    const int lane = tid & 63;
    const int f0 = lane * 2;
    const float* Wc = W1 + 2 * H * H;

    f32x2 wc2[NUM_INV];
    #pragma unroll
    for (int k = 0; k < NUM_INV; ++k)
        wc2[k] = (f32x2){Wc[k * H + f0], Wc[k * H + f0 + 1]};

    f32x2 s2 = {0.f, 0.f}, q2 = {0.f, 0.f};
    const int nw = gridDim.x * 4;
    int e = blockIdx.x * 4 + wave;
    for (; e + nw < N_EDGES; e += 2 * nw) {
        int e0 = __builtin_amdgcn_readfirstlane(e);
        int e1 = __builtin_amdgcn_readfirstlane(e + nw);
        int is0 = isend[e0], ir0 = irec[e0];
        int is1 = isend[e1], ir1 = irec[e1];
        unsigned ua0 = *(const unsigned*)(Ps + (size_t)is0 * H + f0);
        unsigned ub0 = *(const unsigned*)(Pr + (size_t)ir0 * H + f0);
        unsigned ua1 = *(const unsigned*)(Ps + (size_t)is1 * H + f0);
        unsigned ub1 = *(const unsigned*)(Pr + (size_t)ir1 * H + f0);
        f32x2 h0 = ea_mac(ea, e0, wc2, b2f2(ua0) + b2f2(ub0));
        f32x2 h1 = ea_mac(ea, e1, wc2, b2f2(ua1) + b2f2(ub1));
        s2 += h0 + h1;
        q2 += h0 * h0 + h1 * h1;
    }
    if (e < N_EDGES) {
        int e0 = __builtin_amdgcn_readfirstlane(e);
        int is0 = isend[e0], ir0 = irec[e0];
        unsigned ua0 = *(const unsigned*)(Ps + (size_t)is0 * H + f0);
        unsigned ub0 = *(const unsigned*)(Pr + (size_t)ir0 * H + f0);
        f32x2 h0 = ea_mac(ea, e0, wc2, b2f2(ua0) + b2f2(ub0));
        s2 += h0;
        q2 += h0 * h0;
    }

    __shared__ float rs[4][128];
    __shared__ float rq[4][128];
    rs[wave][f0] = s2.x; rs[wave][f0 + 1] = s2.y;
    rq[wave][f0] = q2.x; rq[wave][f0 + 1] = q2.y;
    __syncthreads();
    if (tid < 128) {
        float ss = rs[0][tid] + rs[1][tid] + rs[2][tid] + rs[3][tid];
        float qq = rq[0][tid] + rq[1][tid] + rq[2][tid] + rq[3][tid];
        float* st = stats + (size_t)(blockIdx.x & 63) * 256;
        atomicAdd(st + tid, ss);
        atomicAdd(st + 128 + tid, qq);
    }
}

// ---------------- K3: finalize BN -> per-feature scale/shift ----------------------------
__global__ void k3_finalize(const float* __restrict__ stats,
                            const float* __restrict__ gamma, const float* __restrict__ beta,
                            float* __restrict__ ssb)
{
    int f = threadIdx.x;
    if (f >= H) return;
    float s = 0.f, q = 0.f;
    for (int b = 0; b < 64; ++b) {
        s += stats[b * 256 + f];
        q += stats[b * 256 + 128 + f];
    }
    const float invE = 1.f / (float)N_EDGES;
    float mean = s * invE;
    float var = q * invE - mean * mean;
    float scale = gamma[f] * rsqrtf(var + BN_EPS);
    ssb[f] = scale;
    ssb[H + f] = beta[f] - mean * scale;
}

// ---------------- K4: CSR pass 2 — atomic-free, packed, rcp, DPP, unroll-2 --------------
__global__ __launch_bounds__(256) void k4_csr(
    const unsigned short* __restrict__ Ps, const unsigned short* __restrict__ Pr,
    const int* __restrict__ perm, const int* __restrict__ is_csr,
    const float* __restrict__ ea, const float* __restrict__ W1,
    const int* __restrict__ off, const int* __restrict__ deg,
    const float* __restrict__ ssb, const float* __restrict__ Winf,
    const float* __restrict__ binf_p, float* __restrict__ out)
{
    const int tid = threadIdx.x;
    const int wave = tid >> 6;
    const int lane = tid & 63;
    const int f0 = lane * 2;
    const float* Wc = W1 + 2 * H * H;

    f32x2 wc2[NUM_INV];
    #pragma unroll
    for (int k = 0; k < NUM_INV; ++k)
        wc2[k] = (f32x2){Wc[k * H + f0], Wc[k * H + f0 + 1]};

    int n = blockIdx.x * 4 + wave;
    int nu = __builtin_amdgcn_readfirstlane(n);
    int start = off[nu];
    int d = deg[nu];

    unsigned ub = *(const unsigned*)(Pr + (size_t)nu * H + f0);
    f32x2 pr2 = b2f2(ub);

    f32x2 sc2 = (f32x2){ssb[f0], ssb[f0 + 1]};
    f32x2 sh2 = (f32x2){ssb[H + f0], ssb[H + f0 + 1]};
    f32x2 wi2 = (f32x2){Winf[f0], Winf[f0 + 1]};
    float bi = binf_p[0];

    f32x2 a2 = {0.f, 0.f};
    int i = 0;
    for (; i + 2 <= d; i += 2) {
        int e0 = __builtin_amdgcn_readfirstlane(perm[start + i]);
        int e1 = __builtin_amdgcn_readfirstlane(perm[start + i + 1]);
        int is0 = __builtin_amdgcn_readfirstlane(is_csr[start + i]);
        int is1 = __builtin_amdgcn_readfirstlane(is_csr[start + i + 1]);
        unsigned ua0 = *(const unsigned*)(Ps + (size_t)is0 * H + f0);
        unsigned ua1 = *(const unsigned*)(Ps + (size_t)is1 * H + f0);
        f32x2 h0 = ea_mac(ea, e0, wc2, pr2 + b2f2(ua0));
        f32x2 h1 = ea_mac(ea, e1, wc2, pr2 + b2f2(ua1));
        h0 = h0 * sc2 + sh2;
        h1 = h1 * sc2 + sh2;
        float A0 = 1.f + __expf(-h0.x), B0 = 1.f + __expf(-h0.y);
        float A1 = 1.f + __expf(-h1.x), B1 = 1.f + __expf(-h1.y);
        float r0 = __builtin_amdgcn_rcpf(A0 * B0);
        float r1 = __builtin_amdgcn_rcpf(A1 * B1);
        f32x2 m0 = (f32x2){h0.x * B0 * r0, h0.y * A0 * r0};
        f32x2 m1 = (f32x2){h1.x * B1 * r1, h1.y * A1 * r1};
        f32x2 pp0 = m0 * wi2;
        f32x2 pp1 = m1 * wi2;
        float pt0 = wave_sum_bcast(pp0.x + pp0.y);
        float pt1 = wave_sum_bcast(pp1.x + pp1.y);
        float ew0 = __builtin_amdgcn_rcpf(1.f + __expf(-(pt0 + bi)));
        float ew1 = __builtin_amdgcn_rcpf(1.f + __expf(-(pt1 + bi)));
        a2 += m0 * splat2(ew0) + m1 * splat2(ew1);
    }
    if (i < d) {
        int e0 = __builtin_amdgcn_readfirstlane(perm[start + i]);
        int is0 = __builtin_amdgcn_readfirstlane(is_csr[start + i]);
        unsigned ua0 = *(const unsigned*)(Ps + (size_t)is0 * H + f0);
        f32x2 h0 = ea_mac(ea, e0, wc2, pr2 + b2f2(ua0));
        h0 = h0 * sc2 + sh2;
        float A0 = 1.f + __expf(-h0.x), B0 = 1.f + __expf(-h0.y);
        float r0 = __builtin_amdgcn_rcpf(A0 * B0);
        f32x2 m0 = (f32x2){h0.x * B0 * r0, h0.y * A0 * r0};
        f32x2 pp0 = m0 * wi2;
        float pt0 = wave_sum_bcast(pp0.x + pp0.y);
        float ew0 = __builtin_amdgcn_rcpf(1.f + __expf(-(pt0 + bi)));
        a2 += m0 * splat2(ew0);
    }
    *(float2*)(out + (size_t)nu * H + f0) = make_float2(a2.x, a2.y);
}

// ---------------- launcher --------------------------------------------------------------
extern "C" void kernel_launch(void* const* d_in, const int* in_sizes, int n_in,
                              void* d_out, int out_size, void* d_ws, size_t ws_size,
                              hipStream_t stream)
{
    const float* x_send = (const float*)d_in[0];
    const float* x_rec  = (const float*)d_in[1];
    const int*   isend  = (const int*)d_in[2];
    const int*   irec   = (const int*)d_in[3];
    const float* ea     = (const float*)d_in[4];
    const float* W1     = (const float*)d_in[5];
    const float* b1     = (const float*)d_in[6];
    const float* gamma  = (const float*)d_in[7];
    const float* beta   = (const float*)d_in[8];
    const float* Winf   = (const float*)d_in[9];
    const float* binf   = (const float*)d_in[10];
    float* out = (float*)d_out;

    char* ws = (char*)d_ws;
    unsigned short* Ps = (unsigned short*)(ws);                     // 25,600,000
    unsigned short* Pr = (unsigned short*)(ws + 25600000);          // 25,600,000
    unsigned short* Wt = (unsigned short*)(ws + 51200000);          // 65,536
    float* stats       = (float*)(ws + 51265536);                   // 65,536
    float* ssb         = (float*)(ws + 51331072);                   // 1,024
    int* deg           = (int*)(ws + 51332096);                     // 400,000
    int* off           = (int*)(ws + 51732096);                     // 400,000
    int* cursor        = (int*)(ws + 52132096);                     // 400,000
    int* bsum          = (int*)(ws + 52532096);                     // 1,024
    int* bbase         = (int*)(ws + 52533120);                     // 1,024
    int* perm          = (int*)(ws + 52534144);                     // 6,400,000
    int* is_csr        = (int*)(ws + 58934144);                     // 6,400,000 -> 65,334,144

    hipMemsetAsync(stats, 0, 64 * 256 * sizeof(float), stream);
    hipMemsetAsync(deg, 0, N_NODES * sizeof(int), stream);

    k0_wt<<<(2 * H * H + 255) / 256, 256, 0, stream>>>(W1, Wt);
    dim3 g1(3125, 2, 1);
    k1_gemm<<<g1, 256, 0, stream>>>(x_send, x_rec, Wt, b1, Ps, Pr);

    k_deg<<<N_EDGES / 256, 256, 0, stream>>>(irec, deg);
    k_scanA<<<196, 512, 0, stream>>>(deg, bsum);
    k_scanB<<<1, 256, 0, stream>>>(bsum, bbase);
    k_scanC<<<196, 512, 0, stream>>>(deg, bbase, off, cursor);
    k_perm<<<N_EDGES / 256, 256, 0, stream>>>(irec, isend, cursor, perm, is_csr);

    k2_stats<<<2048, 256, 0, stream>>>(Ps, Pr, isend, irec, ea, W1, stats);
    k3_finalize<<<1, 128, 0, stream>>>(stats, gamma, beta, ssb);
    k4_csr<<<N_NODES / 4, 256, 0, stream>>>(Ps, Pr, perm, is_csr, ea, W1, off, deg,
                                            ssb, Winf, binf, out);
}